// Round 12
// baseline (9614.515 us; speedup 1.0000x reference)
//
#include <hip/hip_runtime.h>
#include <cmath>

// ---------------- problem constants (from reference setup) ----------------
constexpr int B   = 32;
constexpr int LP  = 64;    // path length
constexpr int L   = 128;   // time steps
constexpr int E   = 32;    // emp_size
constexpr int BE  = B * E; // 1024 rows
constexpr int H   = 128;   // HIDDEN
constexpr int M   = 256;   // MLP_SIZE
constexpr int N   = 4;     // NOISE
constexpr int SIG = 30;    // 2+4+8+16
constexpr int IN  = 1 + H + SIG; // 159
constexpr int KP  = 160;   // padded K for layer 1 (multiple of 4)
constexpr int ROWS = 4;    // rows per block
constexpr int NBLK = BE / ROWS; // 256 blocks (= 1 per CU)
constexpr int TPB  = 1024; // threads per block (16 waves)

// ws layout (floats): weights k-major interleaved [K/4][C][4] (one float4 =
// 4 consecutive k for one column; lane-stride 16B = coalesced dwordx4).
// r11 measured this layout at FETCH 8MB / WRITE 1MB / conflicts ~0 — keep it.
// r12 change is purely in the consumer: 2 cols/thread + guaranteed-b128
// LDS x reads to cut VALU instruction count (r11: 67% VALUBusy, ~3.7x
// issue overhead per useful FMA).
constexpr size_t OFF_FW1 = 0;                         // [40][256][4]
constexpr size_t OFF_FW2 = OFF_FW1 + 40 * 256 * 4;    // [64][256][4]
constexpr size_t OFF_FW3 = OFF_FW2 + 64 * 256 * 4;    // [64][128][4]
constexpr size_t OFF_GW1 = OFF_FW3 + 64 * 128 * 4;    // [40][256][4]
constexpr size_t OFF_GW2 = OFF_GW1 + 40 * 256 * 4;    // [64][256][4]
constexpr size_t OFF_GW3 = OFF_GW2 + 64 * 256 * 4;    // [64][512][4]
constexpr size_t OFF_H0  = OFF_GW3 + 64 * 512 * 4;    // [32][128]
constexpr size_t OFF_C0  = OFF_H0 + 32 * H;           // [32][30]
constexpr size_t OFF_YC  = OFF_C0 + 32 * SIG;         // [32]
constexpr size_t WS_TOT  = OFF_YC + 32;               // 381920 floats (~1.53 MB)

// ---------------- prep kernel: signature + h0 + readout const + W relayout
__global__ __launch_bounds__(256) void prep_kernel(
    const float* __restrict__ paths, const float* __restrict__ Wi, const float* __restrict__ bi,
    const float* __restrict__ Wr, const float* __restrict__ br,
    const float* __restrict__ fW1, const float* __restrict__ fW2, const float* __restrict__ fW3,
    const float* __restrict__ gW1, const float* __restrict__ gW2, const float* __restrict__ gW3,
    float* __restrict__ wsbase, float* __restrict__ h0u, float* __restrict__ c0u,
    float* __restrict__ yc, int do_tr)
{
  const int tid = threadIdx.x;
  if (blockIdx.x == 0) {
    __shared__ float sC0[32][SIG];
    __shared__ float sXT[32];
    if (tid < 32) {
      const float* pp = paths + (size_t)tid * LP * 2;
      float S1[2], S2[4], S3[8], S4[16];
      float T1[2], T2[4], T3[8], T4[16];
      {
        float a0 = pp[2] - pp[0], a1 = pp[3] - pp[1];
        S1[0] = a0; S1[1] = a1;
        S2[0] = a0 * a0 * 0.5f; S2[1] = a0 * a1 * 0.5f;
        S2[2] = a1 * a0 * 0.5f; S2[3] = a1 * a1 * 0.5f;
        for (int c = 0; c < 4; c++) { S3[c*2] = S2[c]*a0*(1.f/3.f); S3[c*2+1] = S2[c]*a1*(1.f/3.f); }
        for (int c = 0; c < 8; c++) { S4[c*2] = S3[c]*a0*0.25f;     S4[c*2+1] = S3[c]*a1*0.25f; }
      }
      for (int j = 1; j < LP - 1; j++) {
        float a0 = pp[(j+1)*2]   - pp[j*2];
        float a1 = pp[(j+1)*2+1] - pp[j*2+1];
        T1[0] = a0; T1[1] = a1;
        T2[0] = a0*a0*0.5f; T2[1] = a0*a1*0.5f; T2[2] = a1*a0*0.5f; T2[3] = a1*a1*0.5f;
        for (int c = 0; c < 4; c++) { T3[c*2] = T2[c]*a0*(1.f/3.f); T3[c*2+1] = T2[c]*a1*(1.f/3.f); }
        for (int c = 0; c < 8; c++) { T4[c*2] = T3[c]*a0*0.25f;     T4[c*2+1] = T3[c]*a1*0.25f; }
        float U2[4], U3[8], U4[16];
        for (int i = 0; i < 4;  i++) U2[i] = S2[i] + T2[i];
        for (int a = 0; a < 2; a++) for (int b = 0; b < 2; b++) U2[a*2+b] += S1[a]*T1[b];
        for (int i = 0; i < 8;  i++) U3[i] = S3[i] + T3[i];
        for (int a = 0; a < 2; a++) for (int m = 0; m < 4; m++) U3[a*4+m] += S1[a]*T2[m];
        for (int a = 0; a < 4; a++) for (int b = 0; b < 2; b++) U3[a*2+b] += S2[a]*T1[b];
        for (int i = 0; i < 16; i++) U4[i] = S4[i] + T4[i];
        for (int a = 0; a < 2; a++) for (int m = 0; m < 8; m++) U4[a*8+m] += S1[a]*T3[m];
        for (int a = 0; a < 4; a++) for (int m = 0; m < 4; m++) U4[a*4+m] += S2[a]*T2[m];
        for (int a = 0; a < 8; a++) for (int b = 0; b < 2; b++) U4[a*2+b] += S3[a]*T1[b];
        for (int i = 0; i < 4;  i++) S2[i] = U2[i];
        for (int i = 0; i < 8;  i++) S3[i] = U3[i];
        for (int i = 0; i < 16; i++) S4[i] = U4[i];
        S1[0] += T1[0]; S1[1] += T1[1];
      }
      sXT[tid] = pp[(LP-1)*2 + 1];
      float* dst = &sC0[tid][0];
      dst[0] = S1[0]; dst[1] = S1[1];
      for (int i = 0; i < 4;  i++) dst[2  + i] = S2[i];
      for (int i = 0; i < 8;  i++) dst[6  + i] = S3[i];
      for (int i = 0; i < 16; i++) dst[14 + i] = S4[i];
    }
    __syncthreads();
    for (int idx = tid; idx < 32 * H; idx += 256) {
      int p = idx >> 7, h = idx & (H - 1);
      float acc = bi[h] + sXT[p] * Wi[h];
      const float* c = &sC0[p][0];
      for (int j = 0; j < SIG; j++) acc += c[j] * Wi[(1 + j) * H + h];
      h0u[idx] = acc;
    }
    if (tid < 32) {
      float acc = br[0];
      for (int j = 0; j < SIG; j++) acc += sC0[tid][j] * Wr[H + j];
      yc[tid] = acc;
    }
    for (int idx = tid; idx < 32 * SIG; idx += 256)
      c0u[idx] = sC0[idx / SIG][idx % SIG];
  } else if (do_tr) {
    // relayout weights to k-major interleaved [K4][C][4]:
    // dst[(k4*C + col)*4 + j] = (k4*4+j < Kreal) ? src[(k4*4+j)*C + col] : 0
    const float* srcs[6] = { fW1, fW2, fW3, gW1, gW2, gW3 };
    const int Ks[6]  = { IN, M, M, IN, M, M };         // real K
    const int Cs[6]  = { M, M, H, M, M, H * N };
    const long offs[7] = { (long)OFF_FW1, (long)OFF_FW2, (long)OFF_FW3,
                           (long)OFF_GW1, (long)OFF_GW2, (long)OFF_GW3, (long)OFF_H0 };
    const long total = (long)OFF_H0;
    const long stride = (long)(gridDim.x - 1) * 256;
    for (long idx = (long)(blockIdx.x - 1) * 256 + tid; idx < total; idx += stride) {
      int m = 0;
      while (idx >= offs[m + 1]) m++;
      long rel = idx - offs[m];
      int j = (int)(rel & 3);
      long t = rel >> 2;
      int C = Cs[m];
      int col = (int)(t % C);
      int k  = (int)(t / C) * 4 + j;
      wsbase[idx] = (k < Ks[m]) ? srcs[m][(size_t)k * C + col] : 0.f;
    }
  }
}

// ---------------- helpers ----------------
__device__ __forceinline__ float lipswish_f(float x) {
  return 0.909f * x * (1.f / (1.f + expf(-x)));
}

// ---------------- interleaved-weight layer: 2 cols/thread split-K ---------
// w4 (as float4): [NK4][C]; thread (kq,cg) owns cols {cg, cg+C/2} so BOTH
// weight loads are lane-stride-16B dense dwordx4 (2nd addr = 1st + const).
// 4 x float4 LDS reads (wave-uniform -> broadcast, alignas(16) -> b128)
// feed 32 FMAs. pp: [KSPLIT][4][C] = exactly 8192 floats for all shapes.
template<int C, int NK4, bool TANH>
__device__ __forceinline__ void layer_il(const float* __restrict__ w4raw,
                                         const float* __restrict__ bias,
                                         const float4* __restrict__ xin4, int xs4,
                                         float* __restrict__ pp,
                                         float* __restrict__ outp, int ostride,
                                         int tid)
{
  constexpr int CG = C / 2;
  constexpr int KSPLIT = 2048 / C;     // 1024 / CG
  constexpr int PER = NK4 / KSPLIT;
  const int kq = tid / CG;             // wave-uniform (CG multiple of 64)
  const int cg = tid % CG;
  const int k40 = kq * PER;
  const float4* wp = (const float4*)w4raw + (size_t)k40 * C + cg;
  const float4* xp = xin4 + k40;

  float a00=0.f,a01=0.f,a02=0.f,a03=0.f;   // col cg,   rows 0..3
  float a10=0.f,a11=0.f,a12=0.f,a13=0.f;   // col cg+CG
  #pragma unroll
  for (int i = 0; i < PER; i++) {
    const float4 w0 = wp[(size_t)i * C];
    const float4 w1 = wp[(size_t)i * C + CG];
    const float4 x0 = xp[0 * xs4 + i];
    const float4 x1 = xp[1 * xs4 + i];
    const float4 x2 = xp[2 * xs4 + i];
    const float4 x3 = xp[3 * xs4 + i];
    a00 += x0.x*w0.x + x0.y*w0.y + x0.z*w0.z + x0.w*w0.w;
    a01 += x1.x*w0.x + x1.y*w0.y + x1.z*w0.z + x1.w*w0.w;
    a02 += x2.x*w0.x + x2.y*w0.y + x2.z*w0.z + x2.w*w0.w;
    a03 += x3.x*w0.x + x3.y*w0.y + x3.z*w0.z + x3.w*w0.w;
    a10 += x0.x*w1.x + x0.y*w1.y + x0.z*w1.z + x0.w*w1.w;
    a11 += x1.x*w1.x + x1.y*w1.y + x1.z*w1.z + x1.w*w1.w;
    a12 += x2.x*w1.x + x2.y*w1.y + x2.z*w1.z + x2.w*w1.w;
    a13 += x3.x*w1.x + x3.y*w1.y + x3.z*w1.z + x3.w*w1.w;
  }
  float* pb = pp + (size_t)(kq * 4) * C + cg;
  pb[0 * C] = a00; pb[1 * C] = a01; pb[2 * C] = a02; pb[3 * C] = a03;
  pb += CG;
  pb[0 * C] = a10; pb[1 * C] = a11; pb[2 * C] = a12; pb[3 * C] = a13;
  __syncthreads();
  #pragma unroll
  for (int o = tid; o < 4 * C; o += 1024) {
    const int r = o / C, c = o % C;
    float s = 0.f;
    #pragma unroll
    for (int q = 0; q < KSPLIT; q++) s += pp[(size_t)(q * 4 + r) * C + c];
    s += bias[c];
    outp[r * ostride + c] = TANH ? tanhf(s) : lipswish_f(s);
  }
  __syncthreads();
}

// ---------------- fast persistent SDE kernel (interleaved weights) --------
__global__ __launch_bounds__(TPB) void sde_kernel_mm(
    const float* __restrict__ ts, const float* __restrict__ dW,
    const float* __restrict__ fb1, const float* __restrict__ fb2, const float* __restrict__ fb3,
    const float* __restrict__ gb1, const float* __restrict__ gb2, const float* __restrict__ gb3,
    const float* __restrict__ Wr,
    const float* __restrict__ WF1, const float* __restrict__ WF2, const float* __restrict__ WF3,
    const float* __restrict__ WG1, const float* __restrict__ WG2, const float* __restrict__ WG3,
    const float* __restrict__ h0u, const float* __restrict__ c0u, const float* __restrict__ ycp,
    float* __restrict__ out)
{
  alignas(16) __shared__ float xv[ROWS * KP];     // [t, z(128), c0(30), pad]
  alignas(16) __shared__ float hA[ROWS * M];
  alignas(16) __shared__ float hB[ROWS * M];
  alignas(16) __shared__ float fo[ROWS * H];      // drift output
  alignas(16) __shared__ float go[ROWS * H * N];  // diffusion output
  alignas(16) __shared__ float zz[ROWS * H];      // z (current / mid)
  alignas(16) __shared__ float zzh[ROWS * H];     // zh
  alignas(16) __shared__ float pp[8192];          // split-K partials (32 KB)

  const float4* xv4 = (const float4*)xv;
  const float4* hA4 = (const float4*)hA;
  const float4* hB4 = (const float4*)hB;

  const int tid = threadIdx.x;
  const int r0 = blockIdx.x * ROWS;
  const int p = r0 >> 5;              // unique path index

  const float ts0 = ts[0];
  const float dtv = ts[1] - ts0;
  const int lane = tid & 63;
  const int wrow = tid >> 6;          // 0..15; emit uses wrow<4
  const float wr_lo = Wr[lane];
  const float wr_hi = Wr[lane + 64];
  const float ycv = ycp[p];

  // ---- init: z = zh = h0, xv = [ts0, h0, c0, pad0] ----
  for (int idx = tid; idx < ROWS * H; idx += TPB) {
    int i = idx >> 7, h = idx & (H - 1);
    float v = h0u[p * H + h];
    zz[idx] = v; zzh[idx] = v;
    xv[i * KP + 1 + h] = v;
  }
  if (tid < ROWS * SIG) {
    int i = tid / SIG, j = tid % SIG;
    xv[i * KP + 1 + H + j] = c0u[p * SIG + j];
  }
  if (tid < ROWS) { xv[tid * KP] = ts0; xv[tid * KP + IN] = 0.f; }
  __syncthreads();

  // ---- f0, g0 ----
  layer_il<M, 40, false>(WF1, fb1, xv4, KP / 4, pp, hA, M, tid);
  layer_il<M, 64, false>(WF2, fb2, hA4, M / 4,  pp, hB, M, tid);
  layer_il<H, 64, true >(WF3, fb3, hB4, M / 4,  pp, fo, H, tid);
  layer_il<M, 40, false>(WG1, gb1, xv4, KP / 4, pp, hA, M, tid);
  layer_il<M, 64, false>(WG2, gb2, hA4, M / 4,  pp, hB, M, tid);
  layer_il<H * N, 64, true>(WG3, gb3, hB4, M / 4, pp, go, H * N, tid);

  // ---- emit t=0 ----
  if (wrow < ROWS) {
    float part = zz[wrow * H + lane] * wr_lo + zz[wrow * H + lane + 64] * wr_hi;
    for (int off = 32; off; off >>= 1) part += __shfl_down(part, off, 64);
    if (lane == 0) {
      size_t o = ((size_t)(r0 + wrow) * L + 0) * 2;
      out[o] = ts0; out[o + 1] = part + ycv;
    }
  }
  __syncthreads();

  // ---- time loop ----
  for (int t = 1; t < L; t++) {
    const float t1 = ts[t];
    const float4* dwp = (const float4*)(dW + ((size_t)(t - 1) * BE + r0) * N);

    // phase A: zh1 = 2z - zh + fh*dt + gh.dW ; zmid = z + 0.5dt*fh + 0.5*gh.dW
    for (int e = tid; e < ROWS * H; e += TPB) {
      int i = e >> 7, h = e & (H - 1);
      float4 dwv = dwp[i];
      float4 g4 = *(const float4*)(go + i * (H * N) + h * 4);
      float gdot = g4.x * dwv.x + g4.y * dwv.y + g4.z * dwv.z + g4.w * dwv.w;
      float fh = fo[e];
      float zo = zz[e];
      float nzh = 2.f * zo - zzh[e] + fh * dtv + gdot;
      zz[e] = zo + 0.5f * dtv * fh + 0.5f * gdot;
      zzh[e] = nzh;
      xv[i * KP + 1 + h] = nzh;
    }
    if (tid < ROWS) xv[tid * KP] = t1;
    __syncthreads();

    // f1, g1 at (t1, zh1)
    layer_il<M, 40, false>(WF1, fb1, xv4, KP / 4, pp, hA, M, tid);
    layer_il<M, 64, false>(WF2, fb2, hA4, M / 4,  pp, hB, M, tid);
    layer_il<H, 64, true >(WF3, fb3, hB4, M / 4,  pp, fo, H, tid);
    layer_il<M, 40, false>(WG1, gb1, xv4, KP / 4, pp, hA, M, tid);
    layer_il<M, 64, false>(WG2, gb2, hA4, M / 4,  pp, hB, M, tid);
    layer_il<H * N, 64, true>(WG3, gb3, hB4, M / 4, pp, go, H * N, tid);

    // phase B: z1 = zmid + 0.5dt*f1 + 0.5*g1.dW
    for (int e = tid; e < ROWS * H; e += TPB) {
      int i = e >> 7, h = e & (H - 1);
      float4 dwv = dwp[i];
      float4 g4 = *(const float4*)(go + i * (H * N) + h * 4);
      float gdot = g4.x * dwv.x + g4.y * dwv.y + g4.z * dwv.z + g4.w * dwv.w;
      zz[e] = zz[e] + 0.5f * dtv * fo[e] + 0.5f * gdot;
    }
    __syncthreads();

    // emit y_t
    if (wrow < ROWS) {
      float part = zz[wrow * H + lane] * wr_lo + zz[wrow * H + lane + 64] * wr_hi;
      for (int off = 32; off; off >>= 1) part += __shfl_down(part, off, 64);
      if (lane == 0) {
        size_t o = ((size_t)(r0 + wrow) * L + t) * 2;
        out[o] = t1; out[o + 1] = part + ycv;
      }
    }
    __syncthreads();
  }
}

// ---------------- fallback (small ws): split-K, untransposed --------------
__device__ __forceinline__ void fb_c256(const float* __restrict__ W, const float* __restrict__ bias,
                                        const float* __restrict__ xin, int xs, int Kreal,
                                        float* __restrict__ pp, float* __restrict__ outp, int tid)
{
  const int kq  = tid >> 8;
  const int col = tid & 255;
  const int K4  = 160 >> 2;
  const int k0  = kq * K4;
  float a0 = 0.f, a1 = 0.f, a2 = 0.f, a3 = 0.f;
  const int kend = (Kreal < k0 + K4) ? Kreal : (k0 + K4);
  for (int k = k0; k < kend; k++) {
    float w = W[(size_t)k * M + col];
    a0 += xin[k] * w; a1 += xin[xs + k] * w;
    a2 += xin[2 * xs + k] * w; a3 += xin[3 * xs + k] * w;
  }
  pp[kq * 1024 + 0 * 256 + col] = a0;
  pp[kq * 1024 + 1 * 256 + col] = a1;
  pp[kq * 1024 + 2 * 256 + col] = a2;
  pp[kq * 1024 + 3 * 256 + col] = a3;
  __syncthreads();
  {
    const int r = tid >> 8, c = tid & 255;
    const int base = r * 256 + c;
    float s = pp[base] + pp[base + 1024] + pp[base + 2048] + pp[base + 3072];
    outp[r * M + c] = lipswish_f(s + bias[c]);
  }
  __syncthreads();
}

__device__ __forceinline__ void fb_c256k(const float* __restrict__ W, const float* __restrict__ bias,
                                         const float* __restrict__ xin, int xs,
                                         float* __restrict__ pp, float* __restrict__ outp, int tid)
{
  const int kq  = tid >> 8;
  const int col = tid & 255;
  const int K4  = M >> 2;
  const int k0  = kq * K4;
  float a0 = 0.f, a1 = 0.f, a2 = 0.f, a3 = 0.f;
  for (int k = k0; k < k0 + K4; k++) {
    float w = W[(size_t)k * M + col];
    a0 += xin[k] * w; a1 += xin[xs + k] * w;
    a2 += xin[2 * xs + k] * w; a3 += xin[3 * xs + k] * w;
  }
  pp[kq * 1024 + 0 * 256 + col] = a0;
  pp[kq * 1024 + 1 * 256 + col] = a1;
  pp[kq * 1024 + 2 * 256 + col] = a2;
  pp[kq * 1024 + 3 * 256 + col] = a3;
  __syncthreads();
  {
    const int r = tid >> 8, c = tid & 255;
    const int base = r * 256 + c;
    float s = pp[base] + pp[base + 1024] + pp[base + 2048] + pp[base + 3072];
    outp[r * M + c] = lipswish_f(s + bias[c]);
  }
  __syncthreads();
}

__device__ __forceinline__ void fb_c128(const float* __restrict__ W, const float* __restrict__ bias,
                                        const float* __restrict__ xin, int xs,
                                        float* __restrict__ pp, float* __restrict__ outp, int tid)
{
  const int kq  = tid >> 7;
  const int col = tid & 127;
  const int K4  = M >> 3;
  const int k0  = kq * K4;
  float a0 = 0.f, a1 = 0.f, a2 = 0.f, a3 = 0.f;
  for (int k = k0; k < k0 + K4; k++) {
    float w = W[(size_t)k * H + col];
    a0 += xin[k] * w; a1 += xin[xs + k] * w;
    a2 += xin[2 * xs + k] * w; a3 += xin[3 * xs + k] * w;
  }
  pp[kq * 512 + 0 * 128 + col] = a0;
  pp[kq * 512 + 1 * 128 + col] = a1;
  pp[kq * 512 + 2 * 128 + col] = a2;
  pp[kq * 512 + 3 * 128 + col] = a3;
  __syncthreads();
  if (tid < 512) {
    const int r = tid >> 7, c = tid & 127;
    const int base = r * 128 + c;
    float s = 0.f;
    #pragma unroll
    for (int q = 0; q < 8; q++) s += pp[base + q * 512];
    outp[r * H + c] = tanhf(s + bias[c]);
  }
  __syncthreads();
}

__device__ __forceinline__ void fb_c512(const float* __restrict__ W, const float* __restrict__ bias,
                                        const float* __restrict__ xin, int xs,
                                        float* __restrict__ pp, float* __restrict__ outp, int tid)
{
  const int kq  = tid >> 9;
  const int col = tid & 511;
  const int K4  = M >> 1;
  const int k0  = kq * K4;
  float a0 = 0.f, a1 = 0.f, a2 = 0.f, a3 = 0.f;
  for (int k = k0; k < k0 + K4; k++) {
    float w = W[(size_t)k * (H * N) + col];
    a0 += xin[k] * w; a1 += xin[xs + k] * w;
    a2 += xin[2 * xs + k] * w; a3 += xin[3 * xs + k] * w;
  }
  pp[kq * 2048 + 0 * 512 + col] = a0;
  pp[kq * 2048 + 1 * 512 + col] = a1;
  pp[kq * 2048 + 2 * 512 + col] = a2;
  pp[kq * 2048 + 3 * 512 + col] = a3;
  __syncthreads();
  #pragma unroll
  for (int s2 = 0; s2 < 2; s2++) {
    const int idx = s2 * 1024 + tid;
    const int r = idx >> 9, c = idx & 511;
    const int base = r * 512 + c;
    float s = pp[base] + pp[base + 2048];
    outp[r * (H * N) + c] = tanhf(s + bias[c]);
  }
  __syncthreads();
}

__global__ __launch_bounds__(TPB) void sde_kernel_fb(
    const float* __restrict__ ts, const float* __restrict__ dW,
    const float* __restrict__ fb1, const float* __restrict__ fb2, const float* __restrict__ fb3,
    const float* __restrict__ gb1, const float* __restrict__ gb2, const float* __restrict__ gb3,
    const float* __restrict__ Wr,
    const float* __restrict__ WF1, const float* __restrict__ WF2, const float* __restrict__ WF3,
    const float* __restrict__ WG1, const float* __restrict__ WG2, const float* __restrict__ WG3,
    const float* __restrict__ h0u, const float* __restrict__ c0u, const float* __restrict__ ycp,
    float* __restrict__ out)
{
  __shared__ float xv[ROWS * 160];
  __shared__ float hA[ROWS * M];
  __shared__ float hB[ROWS * M];
  __shared__ float fo[ROWS * H];
  __shared__ float go[ROWS * H * N];
  __shared__ float zz[ROWS * H];
  __shared__ float zzh[ROWS * H];
  __shared__ float pp[4096];

  const int tid = threadIdx.x;
  const int r0 = blockIdx.x * ROWS;
  const int p = r0 >> 5;
  const float ts0 = ts[0];
  const float dtv = ts[1] - ts0;
  const int lane = tid & 63;
  const int wrow = tid >> 6;
  const float wr_lo = Wr[lane];
  const float wr_hi = Wr[lane + 64];
  const float ycv = ycp[p];

  for (int idx = tid; idx < ROWS * H; idx += TPB) {
    int i = idx >> 7, h = idx & (H - 1);
    float v = h0u[p * H + h];
    zz[idx] = v; zzh[idx] = v;
    xv[i * 160 + 1 + h] = v;
  }
  if (tid < ROWS * SIG) {
    int i = tid / SIG, j = tid % SIG;
    xv[i * 160 + 1 + H + j] = c0u[p * SIG + j];
  }
  if (tid < ROWS) { xv[tid * 160] = ts0; xv[tid * 160 + IN] = 0.f; }
  __syncthreads();

  fb_c256(WF1, fb1, xv, 160, IN, pp, hA, tid);
  fb_c256k(WF2, fb2, hA, M, pp, hB, tid);
  fb_c128(WF3, fb3, hB, M, pp, fo, tid);
  fb_c256(WG1, gb1, xv, 160, IN, pp, hA, tid);
  fb_c256k(WG2, gb2, hA, M, pp, hB, tid);
  fb_c512(WG3, gb3, hB, M, pp, go, tid);

  if (wrow < ROWS) {
    float part = zz[wrow * H + lane] * wr_lo + zz[wrow * H + lane + 64] * wr_hi;
    for (int off = 32; off; off >>= 1) part += __shfl_down(part, off, 64);
    if (lane == 0) {
      size_t o = ((size_t)(r0 + wrow) * L + 0) * 2;
      out[o] = ts0; out[o + 1] = part + ycv;
    }
  }
  __syncthreads();

  for (int t = 1; t < L; t++) {
    const float t1 = ts[t];
    const float4* dwp = (const float4*)(dW + ((size_t)(t - 1) * BE + r0) * N);
    for (int e = tid; e < ROWS * H; e += TPB) {
      int i = e >> 7, h = e & (H - 1);
      float4 dwv = dwp[i];
      float4 g4 = *(const float4*)(go + i * (H * N) + h * 4);
      float gdot = g4.x * dwv.x + g4.y * dwv.y + g4.z * dwv.z + g4.w * dwv.w;
      float fh = fo[e];
      float zo = zz[e];
      float nzh = 2.f * zo - zzh[e] + fh * dtv + gdot;
      zz[e] = zo + 0.5f * dtv * fh + 0.5f * gdot;
      zzh[e] = nzh;
      xv[i * 160 + 1 + h] = nzh;
    }
    if (tid < ROWS) xv[tid * 160] = t1;
    __syncthreads();

    fb_c256(WF1, fb1, xv, 160, IN, pp, hA, tid);
    fb_c256k(WF2, fb2, hA, M, pp, hB, tid);
    fb_c128(WF3, fb3, hB, M, pp, fo, tid);
    fb_c256(WG1, gb1, xv, 160, IN, pp, hA, tid);
    fb_c256k(WG2, gb2, hA, M, pp, hB, tid);
    fb_c512(WG3, gb3, hB, M, pp, go, tid);

    for (int e = tid; e < ROWS * H; e += TPB) {
      int i = e >> 7, h = e & (H - 1);
      float4 dwv = dwp[i];
      float4 g4 = *(const float4*)(go + i * (H * N) + h * 4);
      float gdot = g4.x * dwv.x + g4.y * dwv.y + g4.z * dwv.z + g4.w * dwv.w;
      zz[e] = zz[e] + 0.5f * dtv * fo[e] + 0.5f * gdot;
    }
    __syncthreads();

    if (wrow < ROWS) {
      float part = zz[wrow * H + lane] * wr_lo + zz[wrow * H + lane + 64] * wr_hi;
      for (int off = 32; off; off >>= 1) part += __shfl_down(part, off, 64);
      if (lane == 0) {
        size_t o = ((size_t)(r0 + wrow) * L + t) * 2;
        out[o] = t1; out[o + 1] = part + ycv;
      }
    }
    __syncthreads();
  }
}

// ---------------- launch ----------------
extern "C" void kernel_launch(void* const* d_in, const int* in_sizes, int n_in,
                              void* d_out, int out_size, void* d_ws, size_t ws_size,
                              hipStream_t stream) {
  const float* ts    = (const float*)d_in[0];
  const float* paths = (const float*)d_in[1];
  const float* dWn   = (const float*)d_in[2];
  const float* Wi    = (const float*)d_in[3];
  const float* bi    = (const float*)d_in[4];
  const float* fW1   = (const float*)d_in[5];
  const float* fb1   = (const float*)d_in[6];
  const float* fW2   = (const float*)d_in[7];
  const float* fb2   = (const float*)d_in[8];
  const float* fW3   = (const float*)d_in[9];
  const float* fb3   = (const float*)d_in[10];
  const float* gW1   = (const float*)d_in[11];
  const float* gb1   = (const float*)d_in[12];
  const float* gW2   = (const float*)d_in[13];
  const float* gb2   = (const float*)d_in[14];
  const float* gW3   = (const float*)d_in[15];
  const float* gb3   = (const float*)d_in[16];
  const float* Wr    = (const float*)d_in[17];
  const float* br    = (const float*)d_in[18];
  float* out = (float*)d_out;
  float* wsf = (float*)d_ws;

  const bool tr = ws_size >= WS_TOT * sizeof(float);
  if (tr) {
    prep_kernel<<<64, 256, 0, stream>>>(paths, Wi, bi, Wr, br,
                                        fW1, fW2, fW3, gW1, gW2, gW3,
                                        wsf, wsf + OFF_H0, wsf + OFF_C0, wsf + OFF_YC, 1);
    sde_kernel_mm<<<NBLK, TPB, 0, stream>>>(
        ts, dWn, fb1, fb2, fb3, gb1, gb2, gb3, Wr,
        wsf + OFF_FW1, wsf + OFF_FW2, wsf + OFF_FW3,
        wsf + OFF_GW1, wsf + OFF_GW2, wsf + OFF_GW3,
        wsf + OFF_H0, wsf + OFF_C0, wsf + OFF_YC, out);
  } else {
    float* h0u = wsf;
    float* c0u = wsf + 32 * H;
    float* yc  = wsf + 32 * H + 32 * SIG;
    prep_kernel<<<1, 256, 0, stream>>>(paths, Wi, bi, Wr, br,
                                       fW1, fW2, fW3, gW1, gW2, gW3,
                                       wsf, h0u, c0u, yc, 0);
    sde_kernel_fb<<<NBLK, TPB, 0, stream>>>(
        ts, dWn, fb1, fb2, fb3, gb1, gb2, gb3, Wr,
        fW1, fW2, fW3, gW1, gW2, gW3,
        h0u, c0u, yc, out);
  }
}

// Round 13
// 3038.734 us; speedup vs baseline: 3.1640x; 3.1640x over previous
//
#include <hip/hip_runtime.h>
#include <cmath>

// ---------------- problem constants (from reference setup) ----------------
constexpr int B   = 32;
constexpr int LP  = 64;    // path length
constexpr int L   = 128;   // time steps
constexpr int E   = 32;    // emp_size
constexpr int BE  = B * E; // 1024 rows
constexpr int H   = 128;   // HIDDEN
constexpr int M   = 256;   // MLP_SIZE
constexpr int N   = 4;     // NOISE
constexpr int SIG = 30;    // 2+4+8+16
constexpr int IN  = 1 + H + SIG; // 159
constexpr int KP  = 160;   // padded K for layer 1 (multiple of 4)
constexpr int ROWS = 4;    // rows per block
constexpr int NBLK = BE / ROWS; // 256 blocks (= 1 per CU)
constexpr int TPB  = 1024; // threads per block (16 waves)

// ws layout (floats): weights k-major interleaved [K/4][C][4].
// r11 measured: FETCH 8MB / WRITE 1MB / conflicts ~0 / 3.6ms steady, VALU 67%.
// r12 (2 cols/thread) spilled at hipcc's hard 64-VGPR budget for 1024-thr
// blocks (WRITE 798MB) — reverted. r13 = r11 + alignas(16)+float4 LDS x-reads
// ONLY (ds_read_b128 instead of scalarized b32x4; ~40 live VGPRs, no spill).
constexpr size_t OFF_FW1 = 0;                         // [40][256][4]
constexpr size_t OFF_FW2 = OFF_FW1 + 40 * 256 * 4;    // [64][256][4]
constexpr size_t OFF_FW3 = OFF_FW2 + 64 * 256 * 4;    // [64][128][4]
constexpr size_t OFF_GW1 = OFF_FW3 + 64 * 128 * 4;    // [40][256][4]
constexpr size_t OFF_GW2 = OFF_GW1 + 40 * 256 * 4;    // [64][256][4]
constexpr size_t OFF_GW3 = OFF_GW2 + 64 * 256 * 4;    // [64][512][4]
constexpr size_t OFF_H0  = OFF_GW3 + 64 * 512 * 4;    // [32][128]
constexpr size_t OFF_C0  = OFF_H0 + 32 * H;           // [32][30]
constexpr size_t OFF_YC  = OFF_C0 + 32 * SIG;         // [32]
constexpr size_t WS_TOT  = OFF_YC + 32;               // 381920 floats (~1.53 MB)

// ---------------- prep kernel: signature + h0 + readout const + W relayout
__global__ __launch_bounds__(256) void prep_kernel(
    const float* __restrict__ paths, const float* __restrict__ Wi, const float* __restrict__ bi,
    const float* __restrict__ Wr, const float* __restrict__ br,
    const float* __restrict__ fW1, const float* __restrict__ fW2, const float* __restrict__ fW3,
    const float* __restrict__ gW1, const float* __restrict__ gW2, const float* __restrict__ gW3,
    float* __restrict__ wsbase, float* __restrict__ h0u, float* __restrict__ c0u,
    float* __restrict__ yc, int do_tr)
{
  const int tid = threadIdx.x;
  if (blockIdx.x == 0) {
    __shared__ float sC0[32][SIG];
    __shared__ float sXT[32];
    if (tid < 32) {
      const float* pp = paths + (size_t)tid * LP * 2;
      float S1[2], S2[4], S3[8], S4[16];
      float T1[2], T2[4], T3[8], T4[16];
      {
        float a0 = pp[2] - pp[0], a1 = pp[3] - pp[1];
        S1[0] = a0; S1[1] = a1;
        S2[0] = a0 * a0 * 0.5f; S2[1] = a0 * a1 * 0.5f;
        S2[2] = a1 * a0 * 0.5f; S2[3] = a1 * a1 * 0.5f;
        for (int c = 0; c < 4; c++) { S3[c*2] = S2[c]*a0*(1.f/3.f); S3[c*2+1] = S2[c]*a1*(1.f/3.f); }
        for (int c = 0; c < 8; c++) { S4[c*2] = S3[c]*a0*0.25f;     S4[c*2+1] = S3[c]*a1*0.25f; }
      }
      for (int j = 1; j < LP - 1; j++) {
        float a0 = pp[(j+1)*2]   - pp[j*2];
        float a1 = pp[(j+1)*2+1] - pp[j*2+1];
        T1[0] = a0; T1[1] = a1;
        T2[0] = a0*a0*0.5f; T2[1] = a0*a1*0.5f; T2[2] = a1*a0*0.5f; T2[3] = a1*a1*0.5f;
        for (int c = 0; c < 4; c++) { T3[c*2] = T2[c]*a0*(1.f/3.f); T3[c*2+1] = T2[c]*a1*(1.f/3.f); }
        for (int c = 0; c < 8; c++) { T4[c*2] = T3[c]*a0*0.25f;     T4[c*2+1] = T3[c]*a1*0.25f; }
        float U2[4], U3[8], U4[16];
        for (int i = 0; i < 4;  i++) U2[i] = S2[i] + T2[i];
        for (int a = 0; a < 2; a++) for (int b = 0; b < 2; b++) U2[a*2+b] += S1[a]*T1[b];
        for (int i = 0; i < 8;  i++) U3[i] = S3[i] + T3[i];
        for (int a = 0; a < 2; a++) for (int m = 0; m < 4; m++) U3[a*4+m] += S1[a]*T2[m];
        for (int a = 0; a < 4; a++) for (int b = 0; b < 2; b++) U3[a*2+b] += S2[a]*T1[b];
        for (int i = 0; i < 16; i++) U4[i] = S4[i] + T4[i];
        for (int a = 0; a < 2; a++) for (int m = 0; m < 8; m++) U4[a*8+m] += S1[a]*T3[m];
        for (int a = 0; a < 4; a++) for (int m = 0; m < 4; m++) U4[a*4+m] += S2[a]*T2[m];
        for (int a = 0; a < 8; a++) for (int b = 0; b < 2; b++) U4[a*2+b] += S3[a]*T1[b];
        for (int i = 0; i < 4;  i++) S2[i] = U2[i];
        for (int i = 0; i < 8;  i++) S3[i] = U3[i];
        for (int i = 0; i < 16; i++) S4[i] = U4[i];
        S1[0] += T1[0]; S1[1] += T1[1];
      }
      sXT[tid] = pp[(LP-1)*2 + 1];
      float* dst = &sC0[tid][0];
      dst[0] = S1[0]; dst[1] = S1[1];
      for (int i = 0; i < 4;  i++) dst[2  + i] = S2[i];
      for (int i = 0; i < 8;  i++) dst[6  + i] = S3[i];
      for (int i = 0; i < 16; i++) dst[14 + i] = S4[i];
    }
    __syncthreads();
    for (int idx = tid; idx < 32 * H; idx += 256) {
      int p = idx >> 7, h = idx & (H - 1);
      float acc = bi[h] + sXT[p] * Wi[h];
      const float* c = &sC0[p][0];
      for (int j = 0; j < SIG; j++) acc += c[j] * Wi[(1 + j) * H + h];
      h0u[idx] = acc;
    }
    if (tid < 32) {
      float acc = br[0];
      for (int j = 0; j < SIG; j++) acc += sC0[tid][j] * Wr[H + j];
      yc[tid] = acc;
    }
    for (int idx = tid; idx < 32 * SIG; idx += 256)
      c0u[idx] = sC0[idx / SIG][idx % SIG];
  } else if (do_tr) {
    // relayout weights to k-major interleaved [K4][C][4]:
    // dst[(k4*C + col)*4 + j] = (k4*4+j < Kreal) ? src[(k4*4+j)*C + col] : 0
    const float* srcs[6] = { fW1, fW2, fW3, gW1, gW2, gW3 };
    const int Ks[6]  = { IN, M, M, IN, M, M };         // real K
    const int Cs[6]  = { M, M, H, M, M, H * N };
    const long offs[7] = { (long)OFF_FW1, (long)OFF_FW2, (long)OFF_FW3,
                           (long)OFF_GW1, (long)OFF_GW2, (long)OFF_GW3, (long)OFF_H0 };
    const long total = (long)OFF_H0;
    const long stride = (long)(gridDim.x - 1) * 256;
    for (long idx = (long)(blockIdx.x - 1) * 256 + tid; idx < total; idx += stride) {
      int m = 0;
      while (idx >= offs[m + 1]) m++;
      long rel = idx - offs[m];
      int j = (int)(rel & 3);
      long t = rel >> 2;
      int C = Cs[m];
      int col = (int)(t % C);
      int k  = (int)(t / C) * 4 + j;
      wsbase[idx] = (k < Ks[m]) ? srcs[m][(size_t)k * C + col] : 0.f;
    }
  }
}

// ---------------- helpers ----------------
__device__ __forceinline__ float lipswish_f(float x) {
  return 0.909f * x * (1.f / (1.f + expf(-x)));
}

// ---------------- interleaved-weight layer, thread-per-column split-K -----
// w4 (as float4): [NK4][C]. 1024 threads = KSPLIT kq-groups x C columns.
// Thread (kq,col) accumulates rows 0..3 over its K-slice: one coalesced
// float4 weight load + 4 BROADCAST float4 LDS x-reads (ds_read_b128 via
// aligned float4*) per k4 -> 16 FMAs. pp reduce identical to r11.
template<int C, int NK4, bool TANH>
__device__ __forceinline__ void layer_il(const float* __restrict__ w4raw,
                                         const float* __restrict__ bias,
                                         const float4* __restrict__ xin4, int xs4,
                                         float* __restrict__ pp,
                                         float* __restrict__ outp, int ostride,
                                         int tid)
{
  constexpr int KSPLIT = 1024 / C;
  constexpr int PER = NK4 / KSPLIT;
  const int kq  = tid / C;          // power-of-2 divides
  const int col = tid % C;
  const int k40 = kq * PER;
  const float4* wp = (const float4*)w4raw + (size_t)k40 * C + col;
  const float4* xp = xin4 + k40;
  float a0 = 0.f, a1 = 0.f, a2 = 0.f, a3 = 0.f;
  #pragma unroll 4
  for (int i = 0; i < PER; i++) {
    const float4 w  = wp[(size_t)i * C];
    const float4 x0 = xp[0 * xs4 + i];
    const float4 x1 = xp[1 * xs4 + i];
    const float4 x2 = xp[2 * xs4 + i];
    const float4 x3 = xp[3 * xs4 + i];
    a0 += x0.x*w.x + x0.y*w.y + x0.z*w.z + x0.w*w.w;
    a1 += x1.x*w.x + x1.y*w.y + x1.z*w.z + x1.w*w.w;
    a2 += x2.x*w.x + x2.y*w.y + x2.z*w.z + x2.w*w.w;
    a3 += x3.x*w.x + x3.y*w.y + x3.z*w.z + x3.w*w.w;
  }
  float* pb = pp + kq * (4 * C) + col;
  pb[0 * C] = a0; pb[1 * C] = a1; pb[2 * C] = a2; pb[3 * C] = a3;
  __syncthreads();
  for (int o = tid; o < 4 * C; o += 1024) {
    const int r = o / C, c = o % C;
    float s = 0.f;
    #pragma unroll
    for (int q = 0; q < KSPLIT; q++) s += pp[q * (4 * C) + r * C + c];
    s += bias[c];
    outp[r * ostride + c] = TANH ? tanhf(s) : lipswish_f(s);
  }
  __syncthreads();
}

// ---------------- fast persistent SDE kernel (interleaved weights) --------
__global__ __launch_bounds__(TPB) void sde_kernel_mm(
    const float* __restrict__ ts, const float* __restrict__ dW,
    const float* __restrict__ fb1, const float* __restrict__ fb2, const float* __restrict__ fb3,
    const float* __restrict__ gb1, const float* __restrict__ gb2, const float* __restrict__ gb3,
    const float* __restrict__ Wr,
    const float* __restrict__ WF1, const float* __restrict__ WF2, const float* __restrict__ WF3,
    const float* __restrict__ WG1, const float* __restrict__ WG2, const float* __restrict__ WG3,
    const float* __restrict__ h0u, const float* __restrict__ c0u, const float* __restrict__ ycp,
    float* __restrict__ out)
{
  alignas(16) __shared__ float xv[ROWS * KP];     // [t, z(128), c0(30), pad]
  alignas(16) __shared__ float hA[ROWS * M];
  alignas(16) __shared__ float hB[ROWS * M];
  alignas(16) __shared__ float fo[ROWS * H];      // drift output
  alignas(16) __shared__ float go[ROWS * H * N];  // diffusion output
  alignas(16) __shared__ float zz[ROWS * H];      // z (current / mid)
  alignas(16) __shared__ float zzh[ROWS * H];     // zh
  alignas(16) __shared__ float pp[4096];          // split-K partials (16 KB)

  const float4* xv4 = (const float4*)xv;
  const float4* hA4 = (const float4*)hA;
  const float4* hB4 = (const float4*)hB;

  const int tid = threadIdx.x;
  const int r0 = blockIdx.x * ROWS;
  const int p = r0 >> 5;              // unique path index

  const float ts0 = ts[0];
  const float dtv = ts[1] - ts0;
  const int lane = tid & 63;
  const int wrow = tid >> 6;          // 0..15; emit uses wrow<4
  const float wr_lo = Wr[lane];
  const float wr_hi = Wr[lane + 64];
  const float ycv = ycp[p];

  // ---- init: z = zh = h0, xv = [ts0, h0, c0, pad0] ----
  for (int idx = tid; idx < ROWS * H; idx += TPB) {
    int i = idx >> 7, h = idx & (H - 1);
    float v = h0u[p * H + h];
    zz[idx] = v; zzh[idx] = v;
    xv[i * KP + 1 + h] = v;
  }
  if (tid < ROWS * SIG) {
    int i = tid / SIG, j = tid % SIG;
    xv[i * KP + 1 + H + j] = c0u[p * SIG + j];
  }
  if (tid < ROWS) { xv[tid * KP] = ts0; xv[tid * KP + IN] = 0.f; }
  __syncthreads();

  // ---- f0, g0 ----
  layer_il<M, 40, false>(WF1, fb1, xv4, KP / 4, pp, hA, M, tid);
  layer_il<M, 64, false>(WF2, fb2, hA4, M / 4,  pp, hB, M, tid);
  layer_il<H, 64, true >(WF3, fb3, hB4, M / 4,  pp, fo, H, tid);
  layer_il<M, 40, false>(WG1, gb1, xv4, KP / 4, pp, hA, M, tid);
  layer_il<M, 64, false>(WG2, gb2, hA4, M / 4,  pp, hB, M, tid);
  layer_il<H * N, 64, true>(WG3, gb3, hB4, M / 4, pp, go, H * N, tid);

  // ---- emit t=0 ----
  if (wrow < ROWS) {
    float part = zz[wrow * H + lane] * wr_lo + zz[wrow * H + lane + 64] * wr_hi;
    for (int off = 32; off; off >>= 1) part += __shfl_down(part, off, 64);
    if (lane == 0) {
      size_t o = ((size_t)(r0 + wrow) * L + 0) * 2;
      out[o] = ts0; out[o + 1] = part + ycv;
    }
  }
  __syncthreads();

  // ---- time loop ----
  for (int t = 1; t < L; t++) {
    const float t1 = ts[t];
    const float4* dwp = (const float4*)(dW + ((size_t)(t - 1) * BE + r0) * N);

    // phase A: zh1 = 2z - zh + fh*dt + gh.dW ; zmid = z + 0.5dt*fh + 0.5*gh.dW
    for (int e = tid; e < ROWS * H; e += TPB) {
      int i = e >> 7, h = e & (H - 1);
      float4 dwv = dwp[i];
      float4 g4 = *(const float4*)(go + i * (H * N) + h * 4);
      float gdot = g4.x * dwv.x + g4.y * dwv.y + g4.z * dwv.z + g4.w * dwv.w;
      float fh = fo[e];
      float zo = zz[e];
      float nzh = 2.f * zo - zzh[e] + fh * dtv + gdot;
      zz[e] = zo + 0.5f * dtv * fh + 0.5f * gdot;
      zzh[e] = nzh;
      xv[i * KP + 1 + h] = nzh;
    }
    if (tid < ROWS) xv[tid * KP] = t1;
    __syncthreads();

    // f1, g1 at (t1, zh1)
    layer_il<M, 40, false>(WF1, fb1, xv4, KP / 4, pp, hA, M, tid);
    layer_il<M, 64, false>(WF2, fb2, hA4, M / 4,  pp, hB, M, tid);
    layer_il<H, 64, true >(WF3, fb3, hB4, M / 4,  pp, fo, H, tid);
    layer_il<M, 40, false>(WG1, gb1, xv4, KP / 4, pp, hA, M, tid);
    layer_il<M, 64, false>(WG2, gb2, hA4, M / 4,  pp, hB, M, tid);
    layer_il<H * N, 64, true>(WG3, gb3, hB4, M / 4, pp, go, H * N, tid);

    // phase B: z1 = zmid + 0.5dt*f1 + 0.5*g1.dW
    for (int e = tid; e < ROWS * H; e += TPB) {
      int i = e >> 7, h = e & (H - 1);
      float4 dwv = dwp[i];
      float4 g4 = *(const float4*)(go + i * (H * N) + h * 4);
      float gdot = g4.x * dwv.x + g4.y * dwv.y + g4.z * dwv.z + g4.w * dwv.w;
      zz[e] = zz[e] + 0.5f * dtv * fo[e] + 0.5f * gdot;
    }
    __syncthreads();

    // emit y_t
    if (wrow < ROWS) {
      float part = zz[wrow * H + lane] * wr_lo + zz[wrow * H + lane + 64] * wr_hi;
      for (int off = 32; off; off >>= 1) part += __shfl_down(part, off, 64);
      if (lane == 0) {
        size_t o = ((size_t)(r0 + wrow) * L + t) * 2;
        out[o] = t1; out[o + 1] = part + ycv;
      }
    }
    __syncthreads();
  }
}

// ---------------- fallback (small ws): split-K, untransposed --------------
__device__ __forceinline__ void fb_c256(const float* __restrict__ W, const float* __restrict__ bias,
                                        const float* __restrict__ xin, int xs, int Kreal,
                                        float* __restrict__ pp, float* __restrict__ outp, int tid)
{
  const int kq  = tid >> 8;
  const int col = tid & 255;
  const int K4  = 160 >> 2;
  const int k0  = kq * K4;
  float a0 = 0.f, a1 = 0.f, a2 = 0.f, a3 = 0.f;
  const int kend = (Kreal < k0 + K4) ? Kreal : (k0 + K4);
  for (int k = k0; k < kend; k++) {
    float w = W[(size_t)k * M + col];
    a0 += xin[k] * w; a1 += xin[xs + k] * w;
    a2 += xin[2 * xs + k] * w; a3 += xin[3 * xs + k] * w;
  }
  pp[kq * 1024 + 0 * 256 + col] = a0;
  pp[kq * 1024 + 1 * 256 + col] = a1;
  pp[kq * 1024 + 2 * 256 + col] = a2;
  pp[kq * 1024 + 3 * 256 + col] = a3;
  __syncthreads();
  {
    const int r = tid >> 8, c = tid & 255;
    const int base = r * 256 + c;
    float s = pp[base] + pp[base + 1024] + pp[base + 2048] + pp[base + 3072];
    outp[r * M + c] = lipswish_f(s + bias[c]);
  }
  __syncthreads();
}

__device__ __forceinline__ void fb_c256k(const float* __restrict__ W, const float* __restrict__ bias,
                                         const float* __restrict__ xin, int xs,
                                         float* __restrict__ pp, float* __restrict__ outp, int tid)
{
  const int kq  = tid >> 8;
  const int col = tid & 255;
  const int K4  = M >> 2;
  const int k0  = kq * K4;
  float a0 = 0.f, a1 = 0.f, a2 = 0.f, a3 = 0.f;
  for (int k = k0; k < k0 + K4; k++) {
    float w = W[(size_t)k * M + col];
    a0 += xin[k] * w; a1 += xin[xs + k] * w;
    a2 += xin[2 * xs + k] * w; a3 += xin[3 * xs + k] * w;
  }
  pp[kq * 1024 + 0 * 256 + col] = a0;
  pp[kq * 1024 + 1 * 256 + col] = a1;
  pp[kq * 1024 + 2 * 256 + col] = a2;
  pp[kq * 1024 + 3 * 256 + col] = a3;
  __syncthreads();
  {
    const int r = tid >> 8, c = tid & 255;
    const int base = r * 256 + c;
    float s = pp[base] + pp[base + 1024] + pp[base + 2048] + pp[base + 3072];
    outp[r * M + c] = lipswish_f(s + bias[c]);
  }
  __syncthreads();
}

__device__ __forceinline__ void fb_c128(const float* __restrict__ W, const float* __restrict__ bias,
                                        const float* __restrict__ xin, int xs,
                                        float* __restrict__ pp, float* __restrict__ outp, int tid)
{
  const int kq  = tid >> 7;
  const int col = tid & 127;
  const int K4  = M >> 3;
  const int k0  = kq * K4;
  float a0 = 0.f, a1 = 0.f, a2 = 0.f, a3 = 0.f;
  for (int k = k0; k < k0 + K4; k++) {
    float w = W[(size_t)k * H + col];
    a0 += xin[k] * w; a1 += xin[xs + k] * w;
    a2 += xin[2 * xs + k] * w; a3 += xin[3 * xs + k] * w;
  }
  pp[kq * 512 + 0 * 128 + col] = a0;
  pp[kq * 512 + 1 * 128 + col] = a1;
  pp[kq * 512 + 2 * 128 + col] = a2;
  pp[kq * 512 + 3 * 128 + col] = a3;
  __syncthreads();
  if (tid < 512) {
    const int r = tid >> 7, c = tid & 127;
    const int base = r * 128 + c;
    float s = 0.f;
    #pragma unroll
    for (int q = 0; q < 8; q++) s += pp[base + q * 512];
    outp[r * H + c] = tanhf(s + bias[c]);
  }
  __syncthreads();
}

__device__ __forceinline__ void fb_c512(const float* __restrict__ W, const float* __restrict__ bias,
                                        const float* __restrict__ xin, int xs,
                                        float* __restrict__ pp, float* __restrict__ outp, int tid)
{
  const int kq  = tid >> 9;
  const int col = tid & 511;
  const int K4  = M >> 1;
  const int k0  = kq * K4;
  float a0 = 0.f, a1 = 0.f, a2 = 0.f, a3 = 0.f;
  for (int k = k0; k < k0 + K4; k++) {
    float w = W[(size_t)k * (H * N) + col];
    a0 += xin[k] * w; a1 += xin[xs + k] * w;
    a2 += xin[2 * xs + k] * w; a3 += xin[3 * xs + k] * w;
  }
  pp[kq * 2048 + 0 * 512 + col] = a0;
  pp[kq * 2048 + 1 * 512 + col] = a1;
  pp[kq * 2048 + 2 * 512 + col] = a2;
  pp[kq * 2048 + 3 * 512 + col] = a3;
  __syncthreads();
  #pragma unroll
  for (int s2 = 0; s2 < 2; s2++) {
    const int idx = s2 * 1024 + tid;
    const int r = idx >> 9, c = idx & 511;
    const int base = r * 512 + c;
    float s = pp[base] + pp[base + 2048];
    outp[r * (H * N) + c] = tanhf(s + bias[c]);
  }
  __syncthreads();
}

__global__ __launch_bounds__(TPB) void sde_kernel_fb(
    const float* __restrict__ ts, const float* __restrict__ dW,
    const float* __restrict__ fb1, const float* __restrict__ fb2, const float* __restrict__ fb3,
    const float* __restrict__ gb1, const float* __restrict__ gb2, const float* __restrict__ gb3,
    const float* __restrict__ Wr,
    const float* __restrict__ WF1, const float* __restrict__ WF2, const float* __restrict__ WF3,
    const float* __restrict__ WG1, const float* __restrict__ WG2, const float* __restrict__ WG3,
    const float* __restrict__ h0u, const float* __restrict__ c0u, const float* __restrict__ ycp,
    float* __restrict__ out)
{
  __shared__ float xv[ROWS * 160];
  __shared__ float hA[ROWS * M];
  __shared__ float hB[ROWS * M];
  __shared__ float fo[ROWS * H];
  __shared__ float go[ROWS * H * N];
  __shared__ float zz[ROWS * H];
  __shared__ float zzh[ROWS * H];
  __shared__ float pp[4096];

  const int tid = threadIdx.x;
  const int r0 = blockIdx.x * ROWS;
  const int p = r0 >> 5;
  const float ts0 = ts[0];
  const float dtv = ts[1] - ts0;
  const int lane = tid & 63;
  const int wrow = tid >> 6;
  const float wr_lo = Wr[lane];
  const float wr_hi = Wr[lane + 64];
  const float ycv = ycp[p];

  for (int idx = tid; idx < ROWS * H; idx += TPB) {
    int i = idx >> 7, h = idx & (H - 1);
    float v = h0u[p * H + h];
    zz[idx] = v; zzh[idx] = v;
    xv[i * 160 + 1 + h] = v;
  }
  if (tid < ROWS * SIG) {
    int i = tid / SIG, j = tid % SIG;
    xv[i * 160 + 1 + H + j] = c0u[p * SIG + j];
  }
  if (tid < ROWS) { xv[tid * 160] = ts0; xv[tid * 160 + IN] = 0.f; }
  __syncthreads();

  fb_c256(WF1, fb1, xv, 160, IN, pp, hA, tid);
  fb_c256k(WF2, fb2, hA, M, pp, hB, tid);
  fb_c128(WF3, fb3, hB, M, pp, fo, tid);
  fb_c256(WG1, gb1, xv, 160, IN, pp, hA, tid);
  fb_c256k(WG2, gb2, hA, M, pp, hB, tid);
  fb_c512(WG3, gb3, hB, M, pp, go, tid);

  if (wrow < ROWS) {
    float part = zz[wrow * H + lane] * wr_lo + zz[wrow * H + lane + 64] * wr_hi;
    for (int off = 32; off; off >>= 1) part += __shfl_down(part, off, 64);
    if (lane == 0) {
      size_t o = ((size_t)(r0 + wrow) * L + 0) * 2;
      out[o] = ts0; out[o + 1] = part + ycv;
    }
  }
  __syncthreads();

  for (int t = 1; t < L; t++) {
    const float t1 = ts[t];
    const float4* dwp = (const float4*)(dW + ((size_t)(t - 1) * BE + r0) * N);
    for (int e = tid; e < ROWS * H; e += TPB) {
      int i = e >> 7, h = e & (H - 1);
      float4 dwv = dwp[i];
      float4 g4 = *(const float4*)(go + i * (H * N) + h * 4);
      float gdot = g4.x * dwv.x + g4.y * dwv.y + g4.z * dwv.z + g4.w * dwv.w;
      float fh = fo[e];
      float zo = zz[e];
      float nzh = 2.f * zo - zzh[e] + fh * dtv + gdot;
      zz[e] = zo + 0.5f * dtv * fh + 0.5f * gdot;
      zzh[e] = nzh;
      xv[i * 160 + 1 + h] = nzh;
    }
    if (tid < ROWS) xv[tid * 160] = t1;
    __syncthreads();

    fb_c256(WF1, fb1, xv, 160, IN, pp, hA, tid);
    fb_c256k(WF2, fb2, hA, M, pp, hB, tid);
    fb_c128(WF3, fb3, hB, M, pp, fo, tid);
    fb_c256(WG1, gb1, xv, 160, IN, pp, hA, tid);
    fb_c256k(WG2, gb2, hA, M, pp, hB, tid);
    fb_c512(WG3, gb3, hB, M, pp, go, tid);

    for (int e = tid; e < ROWS * H; e += TPB) {
      int i = e >> 7, h = e & (H - 1);
      float4 dwv = dwp[i];
      float4 g4 = *(const float4*)(go + i * (H * N) + h * 4);
      float gdot = g4.x * dwv.x + g4.y * dwv.y + g4.z * dwv.z + g4.w * dwv.w;
      zz[e] = zz[e] + 0.5f * dtv * fo[e] + 0.5f * gdot;
    }
    __syncthreads();

    if (wrow < ROWS) {
      float part = zz[wrow * H + lane] * wr_lo + zz[wrow * H + lane + 64] * wr_hi;
      for (int off = 32; off; off >>= 1) part += __shfl_down(part, off, 64);
      if (lane == 0) {
        size_t o = ((size_t)(r0 + wrow) * L + t) * 2;
        out[o] = t1; out[o + 1] = part + ycv;
      }
    }
    __syncthreads();
  }
}

// ---------------- launch ----------------
extern "C" void kernel_launch(void* const* d_in, const int* in_sizes, int n_in,
                              void* d_out, int out_size, void* d_ws, size_t ws_size,
                              hipStream_t stream) {
  const float* ts    = (const float*)d_in[0];
  const float* paths = (const float*)d_in[1];
  const float* dWn   = (const float*)d_in[2];
  const float* Wi    = (const float*)d_in[3];
  const float* bi    = (const float*)d_in[4];
  const float* fW1   = (const float*)d_in[5];
  const float* fb1   = (const float*)d_in[6];
  const float* fW2   = (const float*)d_in[7];
  const float* fb2   = (const float*)d_in[8];
  const float* fW3   = (const float*)d_in[9];
  const float* fb3   = (const float*)d_in[10];
  const float* gW1   = (const float*)d_in[11];
  const float* gb1   = (const float*)d_in[12];
  const float* gW2   = (const float*)d_in[13];
  const float* gb2   = (const float*)d_in[14];
  const float* gW3   = (const float*)d_in[15];
  const float* gb3   = (const float*)d_in[16];
  const float* Wr    = (const float*)d_in[17];
  const float* br    = (const float*)d_in[18];
  float* out = (float*)d_out;
  float* wsf = (float*)d_ws;

  const bool tr = ws_size >= WS_TOT * sizeof(float);
  if (tr) {
    prep_kernel<<<64, 256, 0, stream>>>(paths, Wi, bi, Wr, br,
                                        fW1, fW2, fW3, gW1, gW2, gW3,
                                        wsf, wsf + OFF_H0, wsf + OFF_C0, wsf + OFF_YC, 1);
    sde_kernel_mm<<<NBLK, TPB, 0, stream>>>(
        ts, dWn, fb1, fb2, fb3, gb1, gb2, gb3, Wr,
        wsf + OFF_FW1, wsf + OFF_FW2, wsf + OFF_FW3,
        wsf + OFF_GW1, wsf + OFF_GW2, wsf + OFF_GW3,
        wsf + OFF_H0, wsf + OFF_C0, wsf + OFF_YC, out);
  } else {
    float* h0u = wsf;
    float* c0u = wsf + 32 * H;
    float* yc  = wsf + 32 * H + 32 * SIG;
    prep_kernel<<<1, 256, 0, stream>>>(paths, Wi, bi, Wr, br,
                                       fW1, fW2, fW3, gW1, gW2, gW3,
                                       wsf, h0u, c0u, yc, 0);
    sde_kernel_fb<<<NBLK, TPB, 0, stream>>>(
        ts, dWn, fb1, fb2, fb3, gb1, gb2, gb3, Wr,
        fW1, fW2, fW3, gW1, gW2, gW3,
        h0u, c0u, yc, out);
  }
}